// Round 1
// baseline (922.718 us; speedup 1.0000x reference)
//
#include <hip/hip_runtime.h>
#include <hip/hip_bf16.h>
#include <stdint.h>

// Problem constants
#define S_ 1024
#define B_ 8
#define E_ 1024
#define H_ 16
#define DH_ 64
#define NHEAD_ 128  // B*H

typedef __bf16 bf16;
typedef bf16 bf16x8 __attribute__((ext_vector_type(8)));
typedef bf16 bf16x4 __attribute__((ext_vector_type(4)));
typedef float fx4 __attribute__((ext_vector_type(4)));

static __device__ __forceinline__ fx4 mfma_bf16(bf16x8 a, bf16x8 b, fx4 c) {
  return __builtin_amdgcn_mfma_f32_16x16x32_bf16(a, b, c, 0, 0, 0);
}

// async global->LDS, 16B per lane; lds base must be wave-uniform (HW adds lane*16)
static __device__ __forceinline__ void gload16(const void* g, void* lds) {
  __builtin_amdgcn_global_load_lds(
      (const __attribute__((address_space(1))) unsigned int*)g,
      (__attribute__((address_space(3))) unsigned int*)lds, 16, 0, 0);
}

// ---------------------------------------------------------------- cast f32->bf16
__global__ __launch_bounds__(256) void k_cast(const float* __restrict__ src,
                                              bf16* __restrict__ dst, int n8) {
  int i = blockIdx.x * 256 + threadIdx.x;
  if (i >= n8) return;
  const fx4* s4 = (const fx4*)src;
  fx4 a = s4[2 * i], b = s4[2 * i + 1];
  bf16x8 o;
  o[0] = (bf16)a[0]; o[1] = (bf16)a[1]; o[2] = (bf16)a[2]; o[3] = (bf16)a[3];
  o[4] = (bf16)b[0]; o[5] = (bf16)b[1]; o[6] = (bf16)b[2]; o[7] = (bf16)b[3];
  ((bf16x8*)dst)[i] = o;
}

// ---------------------------------------------------------------- GEMM: C[M,N] = A[M,K] * W[N,K]^T + bias
// MODE 0: QKV projection epilogue (scatter q/k/v to attention layouts)
// MODE 1: out projection epilogue (f32 store + bias)
// 128x128 tile, BK=32, 4 waves (2x2 quadrants of 64x64), 4x4 frags of 16x16.
template <int MODE>
__global__ __launch_bounds__(256) void k_gemm(const bf16* __restrict__ A,
                                              const bf16* __restrict__ W,
                                              const float* __restrict__ bias, int K,
                                              bf16* __restrict__ Qg, bf16* __restrict__ Kg,
                                              bf16* __restrict__ Vt, float* __restrict__ Cout) {
  __shared__ __align__(16) bf16 As[128 * 32];
  __shared__ __align__(16) bf16 Bs[128 * 32];
  const int tid = threadIdx.x;
  const int l = tid & 63, w = tid >> 6;
  const int r16 = l & 15, kg = l >> 4;
  const int row0 = blockIdx.x * 128, col0 = blockIdx.y * 128;
  const int wm = (w >> 1) * 64, wn = (w & 1) * 64;

  fx4 acc[4][4];
#pragma unroll
  for (int i = 0; i < 4; i++)
#pragma unroll
    for (int j = 0; j < 4; j++) acc[i][j] = (fx4){0.f, 0.f, 0.f, 0.f};

  // staging: thread covers LDS row rA (64B rows), 16B slot (l&3); source k-unit XOR-swizzled
  const int rA = w * 16 + (l >> 2);
  const int srcoff = (((l & 3) ^ ((rA >> 1) & 3)) * 8);
  const size_t gA0 = (size_t)(row0 + rA) * K + srcoff;
  const size_t gA1 = (size_t)(row0 + rA + 64) * K + srcoff;
  const size_t gB0 = (size_t)(col0 + rA) * K + srcoff;
  const size_t gB1 = (size_t)(col0 + rA + 64) * K + srcoff;
  char* ldsA = (char*)As + w * 1024;
  char* ldsB = (char*)Bs + w * 1024;

  for (int k0 = 0; k0 < K; k0 += 32) {
    gload16(A + gA0 + k0, ldsA);
    gload16(A + gA1 + k0, ldsA + 4096);
    gload16(W + gB0 + k0, ldsB);
    gload16(W + gB1 + k0, ldsB + 4096);
    __syncthreads();
    bf16x8 af[4], bfr[4];
#pragma unroll
    for (int i = 0; i < 4; i++) {
      int r = wm + i * 16 + r16;
      af[i] = *(const bf16x8*)((char*)As + r * 64 + ((kg ^ ((r >> 1) & 3)) * 16));
    }
#pragma unroll
    for (int j = 0; j < 4; j++) {
      int r = wn + j * 16 + r16;
      bfr[j] = *(const bf16x8*)((char*)Bs + r * 64 + ((kg ^ ((r >> 1) & 3)) * 16));
    }
#pragma unroll
    for (int i = 0; i < 4; i++)
#pragma unroll
      for (int j = 0; j < 4; j++) acc[i][j] = mfma_bf16(af[i], bfr[j], acc[i][j]);
    __syncthreads();
  }

  // epilogue: C frag layout col = l&15, row = kg*4 + t
#pragma unroll
  for (int j = 0; j < 4; j++) {
    const int cg = col0 + wn + j * 16 + r16;
    const float bs = bias[cg];
    if (MODE == 0) {
      const int sec = cg >> 10;           // 0=q 1=k 2=v
      const int e = cg & 1023;
      const int h = e >> 6, dh = e & 63;
#pragma unroll
      for (int i = 0; i < 4; i++) {
#pragma unroll
        for (int t = 0; t < 4; t++) {
          const int rg = row0 + wm + i * 16 + kg * 4 + t;
          const int s = rg >> 3, bb = rg & 7;
          const int head = bb * 16 + h;
          const float v = acc[i][j][t] + bs;
          if (sec == 0)
            Qg[((size_t)head * 1024 + s) * 64 + dh] = (bf16)(v * 0.125f);
          else if (sec == 1)
            Kg[((size_t)head * 1024 + s) * 64 + dh] = (bf16)v;
          else
            Vt[((size_t)head * 64 + dh) * 1024 + s] = (bf16)v;
        }
      }
    } else {
#pragma unroll
      for (int i = 0; i < 4; i++)
#pragma unroll
        for (int t = 0; t < 4; t++) {
          const int rg = row0 + wm + i * 16 + kg * 4 + t;
          Cout[(size_t)rg * 1024 + cg] = acc[i][j][t] + bs;
        }
    }
  }
}

// ---------------------------------------------------------------- attention
// One wg (4 waves) per (head, 16-query block). Wave w owns key strip [w*256, w*256+256)
// for QK^T, and dh strip [w*16, w*16+16) for PV.
// P buffer in LDS: bf16 [16 rows][1024 keys], XOR-swizzled: byte = row*2048 + (off ^ ((row&7)<<4))
__global__ __launch_bounds__(256) void k_attn(const bf16* __restrict__ Qg,
                                              const bf16* __restrict__ Kg,
                                              const bf16* __restrict__ Vt,
                                              const int* __restrict__ mask,
                                              float* __restrict__ attn_out,
                                              bf16* __restrict__ o_mid) {
  __shared__ __align__(16) bf16 P[16 * 1024];
  __shared__ float mm[1024];
  __shared__ float rinv[16];
  __shared__ int mrow[16];

  const int tid = threadIdx.x;
  const int l = tid & 63, w = tid >> 6;
  const int r16 = l & 15, kg = l >> 4;
  const int head = blockIdx.x >> 6;
  const int q0 = (blockIdx.x & 63) << 4;
  const int b = head >> 4;
  const int h = head & 15;

  for (int i = tid; i < 1024; i += 256) mm[i] = mask[b * 1024 + i] ? 1.0f : 0.0f;
  if (tid < 16) mrow[tid] = mask[b * 1024 + q0 + tid];
  __syncthreads();

  // Q fragments (row = query = l&15, k = dh = kg*8..+7 ; two K=32 halves)
  const bf16* qp = Qg + ((size_t)head * 1024 + q0 + r16) * 64 + kg * 8;
  const bf16x8 aq0 = *(const bf16x8*)qp;
  const bf16x8 aq1 = *(const bf16x8*)(qp + 32);

  // QK^T + exp + masked-key zero -> P (unnormalized probs)
#pragma unroll 4
  for (int t = 0; t < 16; t++) {
    const int key0 = w * 256 + t * 16;
    const bf16* kp = Kg + ((size_t)head * 1024 + key0 + r16) * 64 + kg * 8;
    bf16x8 b0 = *(const bf16x8*)kp;
    bf16x8 b1 = *(const bf16x8*)(kp + 32);
    fx4 c = {0.f, 0.f, 0.f, 0.f};
    c = mfma_bf16(aq0, b0, c);
    c = mfma_bf16(aq1, b1, c);
    const int key = key0 + r16;
    const float mj = mm[key];
#pragma unroll
    for (int e = 0; e < 4; e++) {
      const int row = kg * 4 + e;
      const float p = __expf(c[e]) * mj;
      *(bf16*)((char*)P + row * 2048 + ((key * 2) ^ ((row & 7) << 4))) = (bf16)p;
    }
  }
  __syncthreads();

  // fully-masked query rows: exact uniform 1/1024 (matches reference softmax over all -1e9)
  {
    const int r = tid >> 4, c16 = tid & 15;
    if (mrow[r] == 0) {
      bf16x8 f;
#pragma unroll
      for (int j = 0; j < 8; j++) f[j] = (bf16)0.0009765625f;
#pragma unroll
      for (int i = 0; i < 8; i++) {
        const int unit = c16 * 8 + i;
        *(bf16x8*)((char*)P + r * 2048 + ((unit ^ (r & 7)) << 4)) = f;
      }
    }
  }
  __syncthreads();

  // row sums -> 1/sum  (wave w handles rows 4w..4w+3)
#pragma unroll
  for (int rr = 0; rr < 4; rr++) {
    const int row = w * 4 + rr;
    const int xr = row & 7;
    bf16x8 v0 = *(const bf16x8*)((char*)P + row * 2048 + (((2 * l) ^ xr) << 4));
    bf16x8 v1 = *(const bf16x8*)((char*)P + row * 2048 + (((2 * l + 1) ^ xr) << 4));
    float s = 0.f;
#pragma unroll
    for (int j = 0; j < 8; j++) s += (float)v0[j] + (float)v1[j];
#pragma unroll
    for (int off = 32; off >= 1; off >>= 1) s += __shfl_xor(s, off, 64);
    if (l == 0) rinv[row] = 1.0f / s;
  }
  __syncthreads();

  // normalized attention write: 16 threads per row, float4 coalesced
  {
    const int r = tid >> 4, c16 = tid & 15;
    const float ri = rinv[r];
    float* op = attn_out + ((size_t)(head * 1024) + q0 + r) * 1024;
#pragma unroll
    for (int i = 0; i < 16; i++) {
      const int key = c16 * 4 + i * 64;
      bf16x4 pv = *(const bf16x4*)((char*)P + r * 2048 + ((key * 2) ^ ((r & 7) << 4)));
      fx4 o;
      o[0] = (float)pv[0] * ri;
      o[1] = (float)pv[1] * ri;
      o[2] = (float)pv[2] * ri;
      o[3] = (float)pv[3] * ri;
      *(fx4*)(op + key) = o;
    }
  }

  // PV: wave w computes dh strip [w*16, w*16+16); A = P rows (query), B = V^T
  {
    fx4 c = {0.f, 0.f, 0.f, 0.f};
    const bf16* vp = Vt + ((size_t)head * 64 + w * 16 + r16) * 1024 + kg * 8;
#pragma unroll 4
    for (int kt = 0; kt < 32; kt++) {
      bf16x8 a = *(const bf16x8*)((char*)P + r16 * 2048 +
                                  ((kt * 64 + kg * 16) ^ ((r16 & 7) << 4)));
      bf16x8 bv = *(const bf16x8*)(vp + kt * 32);
      c = mfma_bf16(a, bv, c);
    }
#pragma unroll
    for (int e = 0; e < 4; e++) {
      const int qrow = kg * 4 + e;
      const float val = c[e] * rinv[qrow];
      o_mid[((size_t)(q0 + qrow) * 8 + b) * 1024 + h * 64 + w * 16 + r16] = (bf16)val;
    }
  }
}

// ----------------------------------------------------------------
extern "C" void kernel_launch(void* const* d_in, const int* in_sizes, int n_in,
                              void* d_out, int out_size, void* d_ws, size_t ws_size,
                              hipStream_t stream) {
  const float* x = (const float*)d_in[0];
  const int* mask = (const int*)d_in[1];
  const float* qkv_w = (const float*)d_in[2];
  const float* qkv_b = (const float*)d_in[3];
  const float* out_w = (const float*)d_in[4];
  const float* out_b = (const float*)d_in[5];

  float* out_o = (float*)d_out;
  float* out_attn = out_o + (size_t)S_ * B_ * E_;  // 8,388,608 floats in

  char* ws = (char*)d_ws;
  bf16* x_bf = (bf16*)(ws);                          // 16 MB  (8192x1024)
  bf16* wqkv_bf = (bf16*)(ws + (16ull << 20));       //  6 MB  (3072x1024)
  bf16* wout_bf = (bf16*)(ws + (22ull << 20));       //  2 MB  (1024x1024)
  bf16* Qg = (bf16*)(ws + (24ull << 20));            // 16 MB  [head][s][64]
  bf16* Kg = (bf16*)(ws + (40ull << 20));            // 16 MB  [head][s][64]
  bf16* Vt = (bf16*)(ws + (56ull << 20));            // 16 MB  [head][64][s]
  bf16* o_mid = (bf16*)(ws + (72ull << 20));         // 16 MB  (8192x1024)

  k_cast<<<4096, 256, 0, stream>>>(x, x_bf, 1048576);
  k_cast<<<1536, 256, 0, stream>>>(qkv_w, wqkv_bf, 393216);
  k_cast<<<512, 256, 0, stream>>>(out_w, wout_bf, 131072);

  dim3 g1(64, 24);
  k_gemm<0><<<g1, 256, 0, stream>>>(x_bf, wqkv_bf, qkv_b, 1024, Qg, Kg, Vt, nullptr);

  k_attn<<<8192, 256, 0, stream>>>(Qg, Kg, Vt, mask, out_attn, o_mid);

  dim3 g2(64, 8);
  k_gemm<1><<<g2, 256, 0, stream>>>(o_mid, wout_bf, out_b, 1024, nullptr, nullptr, nullptr, out_o);
}